// Round 1
// baseline (183166.016 us; speedup 1.0000x reference)
//
#include <hip/hip_runtime.h>

#define T_STEPS 16384
#define HID 1024
#define EDIM 256
#define NWG 64
#define TPB 256
#define LAST 1024

// ws layout (bytes):
//   [0, 256)                       flags[NWG]           (memset to 0 each launch)
//   [4096, 12288)                  hbuf[2][HID]         (double-buffered h state)
//   [16384, 16384+4MiB)            grued[LAST][HID]     (last 1024 hidden states)
//   [16384+4MiB, +12KiB)           gx2[LAST][3]
// total ~4.03 MiB

__device__ __forceinline__ float sigmoidf_fast(float v) {
  return 1.0f / (1.0f + __expf(-v));
}
__device__ __forceinline__ float tanhf_fast(float v) {
  float ax = fabsf(v);
  float ex = __expf(-2.0f * ax);
  float t  = (1.0f - ex) / (1.0f + ex);
  return copysignf(t, v);
}

__global__ __launch_bounds__(TPB, 1) void gru_persist(
    const int*   __restrict__ x,
    const float* __restrict__ embed,
    const float* __restrict__ w_ih,
    const float* __restrict__ w_hh,
    const float* __restrict__ b_ih,
    const float* __restrict__ b_hh,
    const float* __restrict__ w_ih2,
    const float* __restrict__ w_hh2,
    const float* __restrict__ b_ih2,
    const float* __restrict__ b_hh2,
    const float* __restrict__ fc2_w,
    const float* __restrict__ fc2_b,
    float* __restrict__ out,
    char*  __restrict__ ws)
{
  int*   flags = (int*)ws;
  float* hbuf  = (float*)(ws + 4096);
  float* grued = (float*)(ws + 16384);
  float* gx2   = (float*)(ws + 16384 + (size_t)LAST * HID * 4);

  const int wg  = blockIdx.x;
  const int tid = threadIdx.x;
  const int g   = tid >> 4;   // h-element group within WG (0..15)
  const int s   = tid & 15;   // sublane: column slice owner (0..15)
  const int e   = wg * 16 + g; // this group's h element (0..1023)

  // ---------------- register-resident weights ----------------
  float wr[64], wz[64], wn[64];
  {
    const float4* pr = (const float4*)(w_hh + (size_t)e * HID + s * 64);
    const float4* pz = (const float4*)(w_hh + (size_t)(HID + e) * HID + s * 64);
    const float4* pn = (const float4*)(w_hh + (size_t)(2 * HID + e) * HID + s * 64);
#pragma unroll
    for (int k = 0; k < 16; ++k) {
      float4 a = pr[k]; wr[4*k] = a.x; wr[4*k+1] = a.y; wr[4*k+2] = a.z; wr[4*k+3] = a.w;
      float4 b = pz[k]; wz[4*k] = b.x; wz[4*k+1] = b.y; wz[4*k+2] = b.z; wz[4*k+3] = b.w;
      float4 c = pn[k]; wn[4*k] = c.x; wn[4*k+1] = c.y; wn[4*k+2] = c.z; wn[4*k+3] = c.w;
    }
  }
  float vir[16], viz[16], vin[16];
  {
    const float4* pr = (const float4*)(w_ih + (size_t)e * EDIM + s * 16);
    const float4* pz = (const float4*)(w_ih + (size_t)(HID + e) * EDIM + s * 16);
    const float4* pn = (const float4*)(w_ih + (size_t)(2 * HID + e) * EDIM + s * 16);
#pragma unroll
    for (int k = 0; k < 4; ++k) {
      float4 a = pr[k]; vir[4*k] = a.x; vir[4*k+1] = a.y; vir[4*k+2] = a.z; vir[4*k+3] = a.w;
      float4 b = pz[k]; viz[4*k] = b.x; viz[4*k+1] = b.y; viz[4*k+2] = b.z; viz[4*k+3] = b.w;
      float4 c = pn[k]; vin[4*k] = c.x; vin[4*k+1] = c.y; vin[4*k+2] = c.z; vin[4*k+3] = c.w;
    }
  }
  const float bir = b_ih[e], biz = b_ih[HID + e], bin_ = b_ih[2 * HID + e];
  const float bhr = b_hh[e], bhz = b_hh[HID + e], bhn  = b_hh[2 * HID + e];

  // first embedding row
  float ec[16];
  {
    int xt = x[0];
    const float4* pe = (const float4*)(embed + (size_t)xt * EDIM + s * 16);
#pragma unroll
    for (int k = 0; k < 4; ++k) {
      float4 a = pe[k]; ec[4*k] = a.x; ec[4*k+1] = a.y; ec[4*k+2] = a.z; ec[4*k+3] = a.w;
    }
  }

  float hold = 0.0f; // running h[e]; identical across the 16 sublanes of a group

  // ---------------- main sequential loop ----------------
  for (int t = 0; t < T_STEPS; ++t) {
    // prefetch next embedding row (latency hidden under this whole step)
    float en[16];
    {
      int xn = x[(t + 1 < T_STEPS) ? (t + 1) : 0];
      const float4* pe = (const float4*)(embed + (size_t)xn * EDIM + s * 16);
#pragma unroll
      for (int k = 0; k < 4; ++k) {
        float4 a = pe[k]; en[4*k] = a.x; en[4*k+1] = a.y; en[4*k+2] = a.z; en[4*k+3] = a.w;
      }
    }

    // gx partials (independent of h) — do them before waiting
    float ar = 0.f, az = 0.f, an = 0.f, hn = 0.f;
#pragma unroll
    for (int k = 0; k < 16; ++k) {
      ar = fmaf(vir[k], ec[k], ar);
      az = fmaf(viz[k], ec[k], az);
      an = fmaf(vin[k], ec[k], an);
    }

    // wait until every WG has published h_{t-1}, then read it
    float hv[64];
    if (t > 0) {
      int spin = 0;
      for (;;) {
        int f = __hip_atomic_load(&flags[tid & 63], __ATOMIC_RELAXED, __HIP_MEMORY_SCOPE_AGENT);
        if (__all(f >= t)) break;
        if (++spin > (1 << 22)) break; // safety valve: fail loudly instead of hanging
      }
      __threadfence(); // acquire: invalidate stale cached h lines
      const float4* ph = (const float4*)(hbuf + ((t - 1) & 1) * HID + s * 64);
#pragma unroll
      for (int k = 0; k < 16; ++k) {
        float4 v = ph[k]; hv[4*k] = v.x; hv[4*k+1] = v.y; hv[4*k+2] = v.z; hv[4*k+3] = v.w;
      }
    } else {
#pragma unroll
      for (int k = 0; k < 64; ++k) hv[k] = 0.f;
    }

    // recurrent matvec slice: 192 FMAs from registers
#pragma unroll
    for (int k = 0; k < 64; ++k) {
      ar = fmaf(wr[k], hv[k], ar);
      az = fmaf(wz[k], hv[k], az);
      hn = fmaf(wn[k], hv[k], hn);
    }

    // butterfly reduce across the 16 sublanes (xor masks stay in-group)
#pragma unroll
    for (int m = 1; m < 16; m <<= 1) {
      ar += __shfl_xor(ar, m, 64);
      az += __shfl_xor(az, m, 64);
      an += __shfl_xor(an, m, 64);
      hn += __shfl_xor(hn, m, 64);
    }

    float r = sigmoidf_fast(ar + bir + bhr);
    float z = sigmoidf_fast(az + biz + bhz);
    float n = tanhf_fast(an + bin_ + r * (hn + bhn));
    float hnew = (1.f - z) * n + z * hold;
    hold = hnew;

    if (s == 0) {
      hbuf[(t & 1) * HID + e] = hnew;
      if (t >= T_STEPS - LAST) grued[(size_t)(t - (T_STEPS - LAST)) * HID + e] = hnew;
    }
    __threadfence();   // release: push h (and grued) to the coherent point
    __syncthreads();   // all 4 waves of this WG have published
    if (tid == 0)
      __hip_atomic_store(&flags[wg], t + 1, __ATOMIC_RELAXED, __HIP_MEMORY_SCOPE_AGENT);

#pragma unroll
    for (int k = 0; k < 16; ++k) ec[k] = en[k];
  }

  // ---------------- stage 2a: gx2 = grued @ w_ih2^T + b_ih2 (all WGs) ----------------
  {
    for (;;) {
      int f = __hip_atomic_load(&flags[tid & 63], __ATOMIC_RELAXED, __HIP_MEMORY_SCOPE_AGENT);
      if (__all(f >= T_STEPS)) break;
    }
    __threadfence();

    const int t2 = wg * 16 + g; // row of grued this group handles
    const float* grow = grued + (size_t)t2 * HID + s * 64;
    float a0 = 0.f, a1 = 0.f, a2 = 0.f;
#pragma unroll
    for (int j = 0; j < 64; ++j) {
      float v = grow[j];
      a0 = fmaf(v, w_ih2[          s * 64 + j], a0);
      a1 = fmaf(v, w_ih2[    HID + s * 64 + j], a1);
      a2 = fmaf(v, w_ih2[2 * HID + s * 64 + j], a2);
    }
#pragma unroll
    for (int m = 1; m < 16; m <<= 1) {
      a0 += __shfl_xor(a0, m, 64);
      a1 += __shfl_xor(a1, m, 64);
      a2 += __shfl_xor(a2, m, 64);
    }
    if (s == 0) {
      gx2[t2 * 3 + 0] = a0 + b_ih2[0];
      gx2[t2 * 3 + 1] = a1 + b_ih2[1];
      gx2[t2 * 3 + 2] = a2 + b_ih2[2];
    }
    __threadfence();
    __syncthreads();
    if (tid == 0)
      __hip_atomic_store(&flags[wg], T_STEPS + 1, __ATOMIC_RELAXED, __HIP_MEMORY_SCOPE_AGENT);
  }

  if (wg != 0) return;

  // ---------------- stage 2b: scalar GRU scan + fc2 (WG0, one lane) ----------------
  for (;;) {
    int f = __hip_atomic_load(&flags[tid & 63], __ATOMIC_RELAXED, __HIP_MEMORY_SCOPE_AGENT);
    if (__all(f >= T_STEPS + 1)) break;
  }
  __threadfence();

  if (tid == 0) {
    float h2 = 0.f;
    float r0 = fc2_b[0], r1 = fc2_b[1];
    const float whr = w_hh2[0], whz = w_hh2[1], whn = w_hh2[2];
    const float bhr2 = b_hh2[0], bhz2 = b_hh2[1], bhn2 = b_hh2[2];
    for (int t = 0; t < LAST; ++t) {
      float gr_ = gx2[t * 3 + 0];
      float gz_ = gx2[t * 3 + 1];
      float gn_ = gx2[t * 3 + 2];
      float r = sigmoidf_fast(gr_ + h2 * whr + bhr2);
      float z = sigmoidf_fast(gz_ + h2 * whz + bhz2);
      float n = tanhf_fast(gn_ + r * (h2 * whn + bhn2));
      h2 = (1.f - z) * n + z * h2;
      r0 = fmaf(h2, fc2_w[t], r0);
      r1 = fmaf(h2, fc2_w[HID + t], r1);
    }
    out[0] = r0;
    out[1] = r1;
  }
}

extern "C" void kernel_launch(void* const* d_in, const int* in_sizes, int n_in,
                              void* d_out, int out_size, void* d_ws, size_t ws_size,
                              hipStream_t stream) {
  const int*   x     = (const int*)d_in[0];
  const float* emb   = (const float*)d_in[1];
  const float* w_ih  = (const float*)d_in[2];
  const float* w_hh  = (const float*)d_in[3];
  const float* b_ih  = (const float*)d_in[4];
  const float* b_hh  = (const float*)d_in[5];
  const float* w_ih2 = (const float*)d_in[6];
  const float* w_hh2 = (const float*)d_in[7];
  const float* b_ih2 = (const float*)d_in[8];
  const float* b_hh2 = (const float*)d_in[9];
  const float* fc2_w = (const float*)d_in[10];
  const float* fc2_b = (const float*)d_in[11];

  // zero the flag region every call (harness poisons ws once; flags must start at 0)
  hipMemsetAsync(d_ws, 0, 4096, stream);

  gru_persist<<<dim3(NWG), dim3(TPB), 0, stream>>>(
      x, emb, w_ih, w_hh, b_ih, b_hh, w_ih2, w_hh2, b_ih2, b_hh2,
      fc2_w, fc2_b, (float*)d_out, (char*)d_ws);
}

// Round 3
// 100567.596 us; speedup vs baseline: 1.8213x; 1.8213x over previous
//
#include <hip/hip_runtime.h>

#define T_STEPS 16384
#define HID 1024
#define EDIM 256
#define NWG 64
#define TPB 256
#define LAST 1024
#define SEG (T_STEPS - LAST)

typedef unsigned long long ull;

// ws layout (bytes):
//   [0, 4)            ctr            (memset to 0 each launch; per-wave step completions)
//   [4096, 12288)     hbuf[2][HID]   double-buffered h, published via agent-scope atomics
//   [16384, +4MiB)    grued[LAST][HID] (normal stores; read by kernel 2 after boundary)

__device__ __forceinline__ float sigmoidf_fast(float v) {
  return 1.0f / (1.0f + __expf(-v));
}
__device__ __forceinline__ float tanhf_fast(float v) {
  float ax = fabsf(v);
  float ex = __expf(-2.0f * ax);
  float t  = (1.0f - ex) / (1.0f + ex);
  return copysignf(t, v);
}

__global__ __launch_bounds__(TPB, 1) void gru_seq(
    const int*   __restrict__ x,
    const float* __restrict__ embed,
    const float* __restrict__ w_ih,
    const float* __restrict__ w_hh,
    const float* __restrict__ b_ih,
    const float* __restrict__ b_hh,
    char*  __restrict__ ws)
{
  int*   ctr   = (int*)ws;
  float* hbuf  = (float*)(ws + 4096);
  float* grued = (float*)(ws + 16384);

  // h broadcast buffer: 16 rows of 64 floats, padded to 68 floats (272 B) per row.
  __shared__ float hlds[16 * 68];

  const int tid  = threadIdx.x;
  const int wg   = blockIdx.x;
  const int g    = tid >> 4;    // h-element group within WG (0..15)
  const int s    = tid & 15;    // sublane: 64-col slice owner (0..15)
  const int e    = wg * 16 + g; // this group's h element
  const int lane = tid & 63;
  const int wid  = tid >> 6;

  // ---------------- register-resident weights ----------------
  float wr[64], wz[64], wn[64];
  {
    const float4* pr = (const float4*)(w_hh + (size_t)e * HID + s * 64);
    const float4* pz = (const float4*)(w_hh + (size_t)(HID + e) * HID + s * 64);
    const float4* pn = (const float4*)(w_hh + (size_t)(2 * HID + e) * HID + s * 64);
#pragma unroll
    for (int k = 0; k < 16; ++k) {
      float4 a = pr[k]; wr[4*k] = a.x; wr[4*k+1] = a.y; wr[4*k+2] = a.z; wr[4*k+3] = a.w;
      float4 b = pz[k]; wz[4*k] = b.x; wz[4*k+1] = b.y; wz[4*k+2] = b.z; wz[4*k+3] = b.w;
      float4 c = pn[k]; wn[4*k] = c.x; wn[4*k+1] = c.y; wn[4*k+2] = c.z; wn[4*k+3] = c.w;
    }
  }
  float vir[16], viz[16], vin[16];
  {
    const float4* pr = (const float4*)(w_ih + (size_t)e * EDIM + s * 16);
    const float4* pz = (const float4*)(w_ih + (size_t)(HID + e) * EDIM + s * 16);
    const float4* pn = (const float4*)(w_ih + (size_t)(2 * HID + e) * EDIM + s * 16);
#pragma unroll
    for (int k = 0; k < 4; ++k) {
      float4 a = pr[k]; vir[4*k] = a.x; vir[4*k+1] = a.y; vir[4*k+2] = a.z; vir[4*k+3] = a.w;
      float4 b = pz[k]; viz[4*k] = b.x; viz[4*k+1] = b.y; viz[4*k+2] = b.z; viz[4*k+3] = b.w;
      float4 c = pn[k]; vin[4*k] = c.x; vin[4*k+1] = c.y; vin[4*k+2] = c.z; vin[4*k+3] = c.w;
    }
  }
  const float bir = b_ih[e], biz = b_ih[HID + e], bin_ = b_ih[2 * HID + e];
  const float bhr = b_hh[e], bhz = b_hh[HID + e], bhn  = b_hh[2 * HID + e];

  // embedding row for step 0
  float ec[16];
  {
    int xt = x[0];
    const float4* pe = (const float4*)(embed + (size_t)xt * EDIM + s * 16);
#pragma unroll
    for (int k = 0; k < 4; ++k) {
      float4 a = pe[k]; ec[4*k] = a.x; ec[4*k+1] = a.y; ec[4*k+2] = a.z; ec[4*k+3] = a.w;
    }
  }

  float hold = 0.0f;

  for (int t = 0; t < T_STEPS; ++t) {
    // ---- phase 1: wave 0 acquires the FULL h_{t-1} (16 floats/lane) and broadcasts ----
    if (t > 0) {
      if (wid == 0) {
        const int need = 4 * NWG * t; // all waves of all WGs finished step t-1
        int spin = 0;
        while (__hip_atomic_load(ctr, __ATOMIC_RELAXED, __HIP_MEMORY_SCOPE_AGENT) < need) {
          if (++spin > (1 << 25)) break; // fail loudly rather than hang
        }
        asm volatile("" ::: "memory"); // don't hoist the h loads above the poll
        const ull* ph = (const ull*)(hbuf + ((t - 1) & 1) * HID) + 8 * lane; // h[16*lane ..]
        ull u[8];
#pragma unroll
        for (int j = 0; j < 8; ++j)
          u[j] = __hip_atomic_load(ph + j, __ATOMIC_RELAXED, __HIP_MEMORY_SCOPE_AGENT);
        const int row  = lane >> 2;            // element (16*lane)/64
        const int col0 = (lane & 3) * 16;      // float offset within row
        float* dst = hlds + row * 68 + col0;
#pragma unroll
        for (int j = 0; j < 4; ++j) {
          union { ull u; float2 f; } a, b;
          a.u = u[2 * j]; b.u = u[2 * j + 1];
          ((float4*)(dst))[j] = make_float4(a.f.x, a.f.y, b.f.x, b.f.y);
        }
      }
      __syncthreads();
    }

    // ---- phase 2: matvec slices ----
    float ar = 0.f, az = 0.f, an = 0.f, hn = 0.f;
#pragma unroll
    for (int k = 0; k < 16; ++k) {
      ar = fmaf(vir[k], ec[k], ar);
      az = fmaf(viz[k], ec[k], az);
      an = fmaf(vin[k], ec[k], an);
    }
    if (t > 0) {
      const float4* hrow = (const float4*)(hlds + s * 68);
#pragma unroll
      for (int k = 0; k < 16; ++k) {
        float4 h4 = hrow[k];
        ar = fmaf(wr[4*k+0], h4.x, ar); ar = fmaf(wr[4*k+1], h4.y, ar);
        ar = fmaf(wr[4*k+2], h4.z, ar); ar = fmaf(wr[4*k+3], h4.w, ar);
        az = fmaf(wz[4*k+0], h4.x, az); az = fmaf(wz[4*k+1], h4.y, az);
        az = fmaf(wz[4*k+2], h4.z, az); az = fmaf(wz[4*k+3], h4.w, az);
        hn = fmaf(wn[4*k+0], h4.x, hn); hn = fmaf(wn[4*k+1], h4.y, hn);
        hn = fmaf(wn[4*k+2], h4.z, hn); hn = fmaf(wn[4*k+3], h4.w, hn);
      }
    }

    // ---- phase 3: reduce across 16 sublanes + gate math ----
#pragma unroll
    for (int m = 1; m < 16; m <<= 1) {
      ar += __shfl_xor(ar, m, 64);
      az += __shfl_xor(az, m, 64);
      an += __shfl_xor(an, m, 64);
      hn += __shfl_xor(hn, m, 64);
    }
    float r = sigmoidf_fast(ar + bir + bhr);
    float z = sigmoidf_fast(az + biz + bhz);
    float n = tanhf_fast(an + bin_ + r * (hn + bhn));
    float hnew = (1.f - z) * n + z * hold;
    hold = hnew;

    // ---- phase 4: publish h element (agent-coherent), grued (normal) ----
    if (s == 0) {
      __hip_atomic_store(hbuf + (t & 1) * HID + e, hnew,
                         __ATOMIC_RELAXED, __HIP_MEMORY_SCOPE_AGENT);
      if (t >= SEG) grued[(size_t)(t - SEG) * HID + e] = hnew;
    }
    // stores acked at the coherent point before this wave's completion is counted
    asm volatile("s_waitcnt vmcnt(0)" ::: "memory");
    if (lane == 0)
      __hip_atomic_fetch_add(ctr, 1, __ATOMIC_RELAXED, __HIP_MEMORY_SCOPE_AGENT);

    // ---- phase 5: prefetch next embedding row (hides under next step's poll) ----
    {
      int xn = x[(t + 1 < T_STEPS) ? (t + 1) : 0];
      const float4* pe = (const float4*)(embed + (size_t)xn * EDIM + s * 16);
#pragma unroll
      for (int k = 0; k < 4; ++k) {
        float4 a = pe[k];
        ec[4*k] = a.x; ec[4*k+1] = a.y; ec[4*k+2] = a.z; ec[4*k+3] = a.w;
      }
    }
  }
}

// ---------------- stage 2: tiny GRU (H=1) over last 1024 states + fc2 ----------------
__global__ __launch_bounds__(TPB, 1) void gru_tail(
    const float* __restrict__ w_ih2,
    const float* __restrict__ w_hh2,
    const float* __restrict__ b_ih2,
    const float* __restrict__ b_hh2,
    const float* __restrict__ fc2_w,
    const float* __restrict__ fc2_b,
    float* __restrict__ out,
    const char* __restrict__ ws)
{
  const float* grued = (const float*)(ws + 16384);
  __shared__ float gx2s[LAST * 3];

  const int tid = threadIdx.x;
  const int g = tid >> 4, s = tid & 15;
  const float bi0 = b_ih2[0], bi1 = b_ih2[1], bi2 = b_ih2[2];

  const float4* w0 = (const float4*)(w_ih2 + 0 * HID + s * 64);
  const float4* w1 = (const float4*)(w_ih2 + 1 * HID + s * 64);
  const float4* w2 = (const float4*)(w_ih2 + 2 * HID + s * 64);

  for (int b = 0; b < LAST / 16; ++b) {
    const int row = b * 16 + g;
    const float4* gr4 = (const float4*)(grued + (size_t)row * HID + s * 64);
    float a0 = 0.f, a1 = 0.f, a2 = 0.f;
#pragma unroll
    for (int k = 0; k < 16; ++k) {
      float4 v = gr4[k], x0 = w0[k], x1 = w1[k], x2 = w2[k];
      a0 = fmaf(v.x, x0.x, a0); a0 = fmaf(v.y, x0.y, a0);
      a0 = fmaf(v.z, x0.z, a0); a0 = fmaf(v.w, x0.w, a0);
      a1 = fmaf(v.x, x1.x, a1); a1 = fmaf(v.y, x1.y, a1);
      a1 = fmaf(v.z, x1.z, a1); a1 = fmaf(v.w, x1.w, a1);
      a2 = fmaf(v.x, x2.x, a2); a2 = fmaf(v.y, x2.y, a2);
      a2 = fmaf(v.w, x2.w, a2); a2 = fmaf(v.z, x2.z, a2);
    }
#pragma unroll
    for (int m = 1; m < 16; m <<= 1) {
      a0 += __shfl_xor(a0, m, 64);
      a1 += __shfl_xor(a1, m, 64);
      a2 += __shfl_xor(a2, m, 64);
    }
    if (s == 0) {
      gx2s[row * 3 + 0] = a0 + bi0;
      gx2s[row * 3 + 1] = a1 + bi1;
      gx2s[row * 3 + 2] = a2 + bi2;
    }
  }
  __syncthreads();

  if (tid == 0) {
    float h2 = 0.f;
    float r0 = fc2_b[0], r1 = fc2_b[1];
    const float whr = w_hh2[0], whz = w_hh2[1], whn = w_hh2[2];
    const float bhr = b_hh2[0], bhz = b_hh2[1], bhn = b_hh2[2];
    for (int t = 0; t < LAST; ++t) {
      float gr_ = gx2s[t * 3 + 0];
      float gz_ = gx2s[t * 3 + 1];
      float gn_ = gx2s[t * 3 + 2];
      float r = sigmoidf_fast(gr_ + h2 * whr + bhr);
      float z = sigmoidf_fast(gz_ + h2 * whz + bhz);
      float n = tanhf_fast(gn_ + r * (h2 * whn + bhn));
      h2 = (1.f - z) * n + z * h2;
      r0 = fmaf(h2, fc2_w[t], r0);
      r1 = fmaf(h2, fc2_w[HID + t], r1);
    }
    out[0] = r0;
    out[1] = r1;
  }
}

extern "C" void kernel_launch(void* const* d_in, const int* in_sizes, int n_in,
                              void* d_out, int out_size, void* d_ws, size_t ws_size,
                              hipStream_t stream) {
  const int*   x     = (const int*)d_in[0];
  const float* emb   = (const float*)d_in[1];
  const float* w_ih  = (const float*)d_in[2];
  const float* w_hh  = (const float*)d_in[3];
  const float* b_ih  = (const float*)d_in[4];
  const float* b_hh  = (const float*)d_in[5];
  const float* w_ih2 = (const float*)d_in[6];
  const float* w_hh2 = (const float*)d_in[7];
  const float* b_ih2 = (const float*)d_in[8];
  const float* b_hh2 = (const float*)d_in[9];
  const float* fc2_w = (const float*)d_in[10];
  const float* fc2_b = (const float*)d_in[11];

  hipMemsetAsync(d_ws, 0, 4096, stream); // ctr must start at 0 every call

  gru_seq<<<dim3(NWG), dim3(TPB), 0, stream>>>(
      x, emb, w_ih, w_hh, b_ih, b_hh, (char*)d_ws);
  gru_tail<<<dim3(1), dim3(TPB), 0, stream>>>(
      w_ih2, w_hh2, b_ih2, b_hh2, fc2_w, fc2_b, (float*)d_out, (const char*)d_ws);
}

// Round 4
// 35575.299 us; speedup vs baseline: 5.1487x; 2.8269x over previous
//
#include <hip/hip_runtime.h>

#define T_STEPS 16384
#define HID 1024
#define EDIM 256
#define NWG 64
#define TPB 256
#define LAST 1024
#define SEG (T_STEPS - LAST)

typedef unsigned long long ull;
typedef unsigned int uint;

// ws layout (bytes):
//   [4096, 20480)   hpairs[2][HID]  : 8B (tag<<32 | float) per h element, 2-slot ring
//                    (memset to 0 each launch -- tags must not survive replays)
//   [32768, +4MiB)  grued[LAST][HID] (normal stores; read by kernel 2 after boundary)

__device__ __forceinline__ float sigmoidf_fast(float v) {
  return 1.0f / (1.0f + __expf(-v));
}
__device__ __forceinline__ float tanhf_fast(float v) {
  float ax = fabsf(v);
  float ex = __expf(-2.0f * ax);
  float t  = (1.0f - ex) / (1.0f + ex);
  return copysignf(t, v);
}

__global__ __launch_bounds__(TPB, 1) void gru_seq(
    const int*   __restrict__ x,
    const float* __restrict__ embed,
    const float* __restrict__ w_ih,
    const float* __restrict__ w_hh,
    const float* __restrict__ b_ih,
    const float* __restrict__ b_hh,
    char*  __restrict__ ws)
{
  ull*   hpairs = (ull*)(ws + 4096);
  float* grued  = (float*)(ws + 32768);

  // double-buffered h broadcast: 16 rows x 68 floats (pad -> 2-way bank alias, free)
  __shared__ float hlds[2][16 * 68];

  const int tid  = threadIdx.x;
  const int wg   = blockIdx.x;
  const int g    = tid >> 4;    // h-element group within WG (0..15)
  const int s    = tid & 15;    // sublane: 64-col slice owner (0..15)
  const int e    = wg * 16 + g; // this group's h element
  const int lane = tid & 63;
  const int wid  = tid >> 6;    // wave id (0..3)

  // ---------------- register-resident weights ----------------
  float wr[64], wz[64], wn[64];
  {
    const float4* pr = (const float4*)(w_hh + (size_t)e * HID + s * 64);
    const float4* pz = (const float4*)(w_hh + (size_t)(HID + e) * HID + s * 64);
    const float4* pn = (const float4*)(w_hh + (size_t)(2 * HID + e) * HID + s * 64);
#pragma unroll
    for (int k = 0; k < 16; ++k) {
      float4 a = pr[k]; wr[4*k] = a.x; wr[4*k+1] = a.y; wr[4*k+2] = a.z; wr[4*k+3] = a.w;
      float4 b = pz[k]; wz[4*k] = b.x; wz[4*k+1] = b.y; wz[4*k+2] = b.z; wz[4*k+3] = b.w;
      float4 c = pn[k]; wn[4*k] = c.x; wn[4*k+1] = c.y; wn[4*k+2] = c.z; wn[4*k+3] = c.w;
    }
  }
  float vir[16], viz[16], vin[16];
  {
    const float4* pr = (const float4*)(w_ih + (size_t)e * EDIM + s * 16);
    const float4* pz = (const float4*)(w_ih + (size_t)(HID + e) * EDIM + s * 16);
    const float4* pn = (const float4*)(w_ih + (size_t)(2 * HID + e) * EDIM + s * 16);
#pragma unroll
    for (int k = 0; k < 4; ++k) {
      float4 a = pr[k]; vir[4*k] = a.x; vir[4*k+1] = a.y; vir[4*k+2] = a.z; vir[4*k+3] = a.w;
      float4 b = pz[k]; viz[4*k] = b.x; viz[4*k+1] = b.y; viz[4*k+2] = b.z; viz[4*k+3] = b.w;
      float4 c = pn[k]; vin[4*k] = c.x; vin[4*k+1] = c.y; vin[4*k+2] = c.z; vin[4*k+3] = c.w;
    }
  }
  const float bir = b_ih[e], biz = b_ih[HID + e], bin_ = b_ih[2 * HID + e];
  const float bhr = b_hh[e], bhz = b_hh[HID + e], bhn  = b_hh[2 * HID + e];

  // embedding row for step 0
  float ec[16];
  {
    int xt = x[0];
    const float4* pe = (const float4*)(embed + (size_t)xt * EDIM + s * 16);
#pragma unroll
    for (int k = 0; k < 4; ++k) {
      float4 a = pe[k]; ec[4*k] = a.x; ec[4*k+1] = a.y; ec[4*k+2] = a.z; ec[4*k+3] = a.w;
    }
  }

  float hold = 0.0f;
  const int pbase = 256 * wid + lane; // this lane's first (h,tag) pair index

  for (int t = 0; t < T_STEPS; ++t) {
    // ---- phase 1: gx partials (independent of h) ----
    float ar = 0.f, az = 0.f, an = 0.f, hn = 0.f;
#pragma unroll
    for (int k = 0; k < 16; ++k) {
      ar = fmaf(vir[k], ec[k], ar);
      az = fmaf(viz[k], ec[k], az);
      an = fmaf(vin[k], ec[k], an);
    }

    const int b = (t - 1) & 1; // ring slot / LDS buffer for h_{t-1}

    // ---- phase 2: poll-load h_{t-1}; the poll IS the data fetch ----
    if (t > 0) {
      const ull* slot = hpairs + (size_t)b * HID;
      const uint want = (uint)t; // tag written at end of step t-1
      ull v0, v1, v2, v3;
      int spin = 0;
      for (;;) {
        v0 = __hip_atomic_load(slot + pbase,       __ATOMIC_RELAXED, __HIP_MEMORY_SCOPE_AGENT);
        v1 = __hip_atomic_load(slot + pbase + 64,  __ATOMIC_RELAXED, __HIP_MEMORY_SCOPE_AGENT);
        v2 = __hip_atomic_load(slot + pbase + 128, __ATOMIC_RELAXED, __HIP_MEMORY_SCOPE_AGENT);
        v3 = __hip_atomic_load(slot + pbase + 192, __ATOMIC_RELAXED, __HIP_MEMORY_SCOPE_AGENT);
        uint bad = ((uint)(v0 >> 32) ^ want) | ((uint)(v1 >> 32) ^ want) |
                   ((uint)(v2 >> 32) ^ want) | ((uint)(v3 >> 32) ^ want);
        if (bad == 0) break;
        if (++spin > (1 << 22)) break; // fail loudly rather than hang
      }
      // scatter to LDS: pair idx = 256*wid + 64*j + lane -> row 4*wid+j, col lane
      float* dst = &hlds[b][(4 * wid) * 68 + lane];
      dst[0 * 68] = __uint_as_float((uint)v0);
      dst[1 * 68] = __uint_as_float((uint)v1);
      dst[2 * 68] = __uint_as_float((uint)v2);
      dst[3 * 68] = __uint_as_float((uint)v3);
      __syncthreads();

      // ---- phase 3: recurrent matvec slice from LDS ----
      const float4* hrow = (const float4*)(&hlds[b][s * 68]);
#pragma unroll
      for (int k = 0; k < 16; ++k) {
        float4 h4 = hrow[k];
        ar = fmaf(wr[4*k+0], h4.x, ar); ar = fmaf(wr[4*k+1], h4.y, ar);
        ar = fmaf(wr[4*k+2], h4.z, ar); ar = fmaf(wr[4*k+3], h4.w, ar);
        az = fmaf(wz[4*k+0], h4.x, az); az = fmaf(wz[4*k+1], h4.y, az);
        az = fmaf(wz[4*k+2], h4.z, az); az = fmaf(wz[4*k+3], h4.w, az);
        hn = fmaf(wn[4*k+0], h4.x, hn); hn = fmaf(wn[4*k+1], h4.y, hn);
        hn = fmaf(wn[4*k+2], h4.z, hn); hn = fmaf(wn[4*k+3], h4.w, hn);
      }
    }

    // ---- phase 4: reduce across 16 sublanes + gate math ----
#pragma unroll
    for (int m = 1; m < 16; m <<= 1) {
      ar += __shfl_xor(ar, m, 64);
      az += __shfl_xor(az, m, 64);
      an += __shfl_xor(an, m, 64);
      hn += __shfl_xor(hn, m, 64);
    }
    float r = sigmoidf_fast(ar + bir + bhr);
    float z = sigmoidf_fast(az + biz + bhz);
    float n = tanhf_fast(an + bin_ + r * (hn + bhn));
    float hnew = (1.f - z) * n + z * hold;
    hold = hnew;

    // ---- phase 5: publish (value,tag) as ONE 8B atomic store ----
    if (s == 0) {
      ull pk = ((ull)(uint)(t + 1) << 32) | (ull)__float_as_uint(hnew);
      __hip_atomic_store(hpairs + (size_t)(t & 1) * HID + e, pk,
                         __ATOMIC_RELAXED, __HIP_MEMORY_SCOPE_AGENT);
      if (t >= SEG) grued[(size_t)(t - SEG) * HID + e] = hnew;
    }
    // drain before next iteration (same-slot rewrite is 2 steps away; keeps
    // same-address store order safe). Hidden under other WGs' poll+compute.
    asm volatile("s_waitcnt vmcnt(0)" ::: "memory");

    // ---- phase 6: prefetch next embedding row ----
    {
      int xn = x[(t + 1 < T_STEPS) ? (t + 1) : 0];
      const float4* pe = (const float4*)(embed + (size_t)xn * EDIM + s * 16);
#pragma unroll
      for (int k = 0; k < 4; ++k) {
        float4 a = pe[k];
        ec[4*k] = a.x; ec[4*k+1] = a.y; ec[4*k+2] = a.z; ec[4*k+3] = a.w;
      }
    }
  }
}

// ---------------- stage 2: tiny GRU (H=1) over last 1024 states + fc2 ----------------
__global__ __launch_bounds__(TPB, 1) void gru_tail(
    const float* __restrict__ w_ih2,
    const float* __restrict__ w_hh2,
    const float* __restrict__ b_ih2,
    const float* __restrict__ b_hh2,
    const float* __restrict__ fc2_w,
    const float* __restrict__ fc2_b,
    float* __restrict__ out,
    const char* __restrict__ ws)
{
  const float* grued = (const float*)(ws + 32768);
  __shared__ float gx2s[LAST * 3];

  const int tid = threadIdx.x;
  const int g = tid >> 4, s = tid & 15;
  const float bi0 = b_ih2[0], bi1 = b_ih2[1], bi2 = b_ih2[2];

  const float4* w0 = (const float4*)(w_ih2 + 0 * HID + s * 64);
  const float4* w1 = (const float4*)(w_ih2 + 1 * HID + s * 64);
  const float4* w2 = (const float4*)(w_ih2 + 2 * HID + s * 64);

  for (int b = 0; b < LAST / 16; ++b) {
    const int row = b * 16 + g;
    const float4* gr4 = (const float4*)(grued + (size_t)row * HID + s * 64);
    float a0 = 0.f, a1 = 0.f, a2 = 0.f;
#pragma unroll
    for (int k = 0; k < 16; ++k) {
      float4 v = gr4[k], x0 = w0[k], x1 = w1[k], x2 = w2[k];
      a0 = fmaf(v.x, x0.x, a0); a0 = fmaf(v.y, x0.y, a0);
      a0 = fmaf(v.z, x0.z, a0); a0 = fmaf(v.w, x0.w, a0);
      a1 = fmaf(v.x, x1.x, a1); a1 = fmaf(v.y, x1.y, a1);
      a1 = fmaf(v.z, x1.z, a1); a1 = fmaf(v.w, x1.w, a1);
      a2 = fmaf(v.x, x2.x, a2); a2 = fmaf(v.y, x2.y, a2);
      a2 = fmaf(v.z, x2.z, a2); a2 = fmaf(v.w, x2.w, a2);
    }
#pragma unroll
    for (int m = 1; m < 16; m <<= 1) {
      a0 += __shfl_xor(a0, m, 64);
      a1 += __shfl_xor(a1, m, 64);
      a2 += __shfl_xor(a2, m, 64);
    }
    if (s == 0) {
      gx2s[row * 3 + 0] = a0 + bi0;
      gx2s[row * 3 + 1] = a1 + bi1;
      gx2s[row * 3 + 2] = a2 + bi2;
    }
  }
  __syncthreads();

  if (tid == 0) {
    float h2 = 0.f;
    float r0 = fc2_b[0], r1 = fc2_b[1];
    const float whr = w_hh2[0], whz = w_hh2[1], whn = w_hh2[2];
    const float bhr = b_hh2[0], bhz = b_hh2[1], bhn = b_hh2[2];
    for (int t = 0; t < LAST; ++t) {
      float gr_ = gx2s[t * 3 + 0];
      float gz_ = gx2s[t * 3 + 1];
      float gn_ = gx2s[t * 3 + 2];
      float r = sigmoidf_fast(gr_ + h2 * whr + bhr);
      float z = sigmoidf_fast(gz_ + h2 * whz + bhz);
      float n = tanhf_fast(gn_ + r * (h2 * whn + bhn));
      h2 = (1.f - z) * n + z * h2;
      r0 = fmaf(h2, fc2_w[t], r0);
      r1 = fmaf(h2, fc2_w[HID + t], r1);
    }
    out[0] = r0;
    out[1] = r1;
  }
}

extern "C" void kernel_launch(void* const* d_in, const int* in_sizes, int n_in,
                              void* d_out, int out_size, void* d_ws, size_t ws_size,
                              hipStream_t stream) {
  const int*   x     = (const int*)d_in[0];
  const float* emb   = (const float*)d_in[1];
  const float* w_ih  = (const float*)d_in[2];
  const float* w_hh  = (const float*)d_in[3];
  const float* b_ih  = (const float*)d_in[4];
  const float* b_hh  = (const float*)d_in[5];
  const float* w_ih2 = (const float*)d_in[6];
  const float* w_hh2 = (const float*)d_in[7];
  const float* b_ih2 = (const float*)d_in[8];
  const float* b_hh2 = (const float*)d_in[9];
  const float* fc2_w = (const float*)d_in[10];
  const float* fc2_b = (const float*)d_in[11];

  // tags must start at 0 EVERY call (stale tags from a prior replay could
  // false-match; the harness re-validates d_out after timed replays)
  hipMemsetAsync(d_ws, 0, 20480, stream);

  gru_seq<<<dim3(NWG), dim3(TPB), 0, stream>>>(
      x, emb, w_ih, w_hh, b_ih, b_hh, (char*)d_ws);
  gru_tail<<<dim3(1), dim3(TPB), 0, stream>>>(
      w_ih2, w_hh2, b_ih2, b_hh2, fc2_w, fc2_b, (float*)d_out, (const char*)d_ws);
}

// Round 5
// 31278.534 us; speedup vs baseline: 5.8560x; 1.1374x over previous
//
#include <hip/hip_runtime.h>

#define T_STEPS 16384
#define HID 1024
#define EDIM 256
#define NWG 64
#define TPB 256
#define LAST 1024
#define SEG (T_STEPS - LAST)
#define VOCAB 257
#define NGATE 3072

typedef unsigned long long ull;
typedef unsigned int uint;

// ws layout (bytes):
//   [4096, 20480)        hpairs[2][HID] : 8B (tag<<32 | float_bits), memset each launch
//   [32768, +4MiB)       grued[LAST][HID]
//   [4227072, +3.01MiB)  gxtab[VOCAB][NGATE]  (pre-kernel output; biases folded)
#define WS_HPAIRS 4096
#define WS_GRUED  32768
#define WS_GXTAB  (32768 + (size_t)LAST * HID * 4)

__device__ __forceinline__ float sigmoidf_fast(float v) {
  return 1.0f / (1.0f + __expf(-v));
}
__device__ __forceinline__ float tanhf_fast(float v) {
  float ax = fabsf(v);
  float ex = __expf(-2.0f * ax);
  float t  = (1.0f - ex) / (1.0f + ex);
  return copysignf(t, v);
}

// ---------------- pre-kernel: gxtab[v][j] = embed[v]·w_ih[j] + b_ih[j] (+b_hh[j] for r,z) ----
__global__ __launch_bounds__(256) void gx_table(
    const float* __restrict__ embed,
    const float* __restrict__ w_ih,
    const float* __restrict__ b_ih,
    const float* __restrict__ b_hh,
    float* __restrict__ gxtab)
{
  __shared__ __align__(16) float erow[EDIM];
  const int v   = blockIdx.x;
  const int tid = threadIdx.x;
  erow[tid] = embed[(size_t)v * EDIM + tid]; // TPB == EDIM == 256
  __syncthreads();
#pragma unroll
  for (int i = 0; i < NGATE / 256; ++i) {
    const int j = tid + 256 * i;
    const float4* w4 = (const float4*)(w_ih + (size_t)j * EDIM);
    float acc = 0.f;
#pragma unroll 8
    for (int k = 0; k < EDIM / 4; ++k) {
      float4 w = w4[k];
      float4 e4 = ((const float4*)erow)[k];
      acc = fmaf(w.x, e4.x, acc); acc = fmaf(w.y, e4.y, acc);
      acc = fmaf(w.z, e4.z, acc); acc = fmaf(w.w, e4.w, acc);
    }
    acc += b_ih[j];
    if (j < 2 * HID) acc += b_hh[j]; // r,z biases fold outside the nonlinearity
    gxtab[(size_t)v * NGATE + j] = acc;
  }
}

// ---------------- main sequential kernel ----------------
__global__ __launch_bounds__(TPB, 1) void gru_seq(
    const int*   __restrict__ x,
    const float* __restrict__ w_hh,
    const float* __restrict__ b_hh,
    char*  __restrict__ ws)
{
  ull*        hpairs = (ull*)(ws + WS_HPAIRS);
  float*      grued  = (float*)(ws + WS_GRUED);
  const float* gxtab = (const float*)(ws + WS_GXTAB);

  // wave-private h quarters: 4 rows of 68-float-padded col-blocks (c*68 + lane)
  __shared__ __align__(16) float hq[4][4 * 68];
  // per-wave partial sums, double-buffered by t&1: [buf][wave][row][4]
  __shared__ __align__(16) float part[2][4][16][4];

  const int tid  = threadIdx.x;
  const int wg   = blockIdx.x;
  const int lane = tid & 63;
  const int wid  = tid >> 6;     // wave id = h quarter owner
  const int r    = lane >> 2;    // matvec row within WG (0..15)
  const int c    = lane & 3;     // 64-col sub-block within quarter (0..3)
  const int e_mv = wg * 16 + r;  // matvec row element
  const int col0 = 256 * wid + 64 * c;

  // ---- register-resident recurrent weights: w_hh[gate,e_mv][col0..col0+64] ----
  float wr[64], wz[64], wn[64];
  {
    const float4* pr = (const float4*)(w_hh + (size_t)e_mv * HID + col0);
    const float4* pz = (const float4*)(w_hh + (size_t)(HID + e_mv) * HID + col0);
    const float4* pn = (const float4*)(w_hh + (size_t)(2 * HID + e_mv) * HID + col0);
#pragma unroll
    for (int k = 0; k < 16; ++k) {
      float4 a = pr[k]; wr[4*k] = a.x; wr[4*k+1] = a.y; wr[4*k+2] = a.z; wr[4*k+3] = a.w;
      float4 b = pz[k]; wz[4*k] = b.x; wz[4*k+1] = b.y; wz[4*k+2] = b.z; wz[4*k+3] = b.w;
      float4 c4 = pn[k]; wn[4*k] = c4.x; wn[4*k+1] = c4.y; wn[4*k+2] = c4.z; wn[4*k+3] = c4.w;
    }
  }

  // ---- combine-role state (lanes 0..3 of each wave own rows 4*wid+lane) ----
  const int e_cb = wg * 16 + 4 * wid + lane; // valid when lane < 4
  float bhn = 0.f, hold = 0.f;
  float gxr0 = 0.f, gxz0 = 0.f, gxn0 = 0.f;
  int xt1 = 0;
  if (lane < 4) {
    bhn = b_hh[2 * HID + e_cb];
    const int x0 = x[0];
    const float* g0 = gxtab + (size_t)x0 * NGATE;
    gxr0 = g0[e_cb];
    gxz0 = g0[HID + e_cb];
    gxn0 = g0[2 * HID + e_cb];
    xt1 = x[1];
  }

  for (int t = 0; t < T_STEPS; ++t) {
    // ---- prefetch gx for step t+1 (arrives during poll) ----
    float gxr1 = 0.f, gxz1 = 0.f, gxn1 = 0.f;
    int xt2 = 0;
    if (lane < 4) {
      const float* g1 = gxtab + (size_t)xt1 * NGATE;
      gxr1 = g1[e_cb];
      gxz1 = g1[HID + e_cb];
      gxn1 = g1[2 * HID + e_cb];
      xt2 = x[(t + 2 < T_STEPS) ? (t + 2) : 0];
    }

    float ar = 0.f, az = 0.f, hn = 0.f;
    if (t > 0) {
      // ---- poll own quarter: tags == t means h_{t-1} is there (tag rides with data) ----
      const ull* slot = hpairs + (size_t)((t - 1) & 1) * HID + 256 * wid + lane;
      const uint want = (uint)t;
      ull v0, v1, v2, v3;
      int spin = 0;
      for (;;) {
        v0 = __hip_atomic_load(slot + 0,   __ATOMIC_RELAXED, __HIP_MEMORY_SCOPE_AGENT);
        v1 = __hip_atomic_load(slot + 64,  __ATOMIC_RELAXED, __HIP_MEMORY_SCOPE_AGENT);
        v2 = __hip_atomic_load(slot + 128, __ATOMIC_RELAXED, __HIP_MEMORY_SCOPE_AGENT);
        v3 = __hip_atomic_load(slot + 192, __ATOMIC_RELAXED, __HIP_MEMORY_SCOPE_AGENT);
        uint bad = ((uint)(v0 >> 32) ^ want) | ((uint)(v1 >> 32) ^ want) |
                   ((uint)(v2 >> 32) ^ want) | ((uint)(v3 >> 32) ^ want);
        if (bad == 0) break;
        if (++spin > (1 << 24)) break; // fail loudly rather than hang
      }
      // ---- wave-private scatter; no block barrier (same-wave LDS is ordered by lgkmcnt) ----
      hq[wid][0 * 68 + lane] = __uint_as_float((uint)v0);
      hq[wid][1 * 68 + lane] = __uint_as_float((uint)v1);
      hq[wid][2 * 68 + lane] = __uint_as_float((uint)v2);
      hq[wid][3 * 68 + lane] = __uint_as_float((uint)v3);
      asm volatile("s_waitcnt lgkmcnt(0)" ::: "memory");
      __builtin_amdgcn_sched_barrier(0);

      // ---- matvec slice: 192 FMAs over this wave's quarter, col-block c ----
      const float4* hp = (const float4*)&hq[wid][68 * c];
#pragma unroll
      for (int k = 0; k < 16; ++k) {
        float4 h4 = hp[k];
        ar = fmaf(wr[4*k+0], h4.x, ar); ar = fmaf(wr[4*k+1], h4.y, ar);
        ar = fmaf(wr[4*k+2], h4.z, ar); ar = fmaf(wr[4*k+3], h4.w, ar);
        az = fmaf(wz[4*k+0], h4.x, az); az = fmaf(wz[4*k+1], h4.y, az);
        az = fmaf(wz[4*k+2], h4.z, az); az = fmaf(wz[4*k+3], h4.w, az);
        hn = fmaf(wn[4*k+0], h4.x, hn); hn = fmaf(wn[4*k+1], h4.y, hn);
        hn = fmaf(wn[4*k+2], h4.z, hn); hn = fmaf(wn[4*k+3], h4.w, hn);
      }
      // ---- reduce over the 4 col-blocks (lanes 4r..4r+3) ----
      ar += __shfl_xor(ar, 1, 64); ar += __shfl_xor(ar, 2, 64);
      az += __shfl_xor(az, 1, 64); az += __shfl_xor(az, 2, 64);
      hn += __shfl_xor(hn, 1, 64); hn += __shfl_xor(hn, 2, 64);
    }

    if (c == 0) {
      part[t & 1][wid][r][0] = ar;
      part[t & 1][wid][r][1] = az;
      part[t & 1][wid][r][2] = hn;
    }
    __syncthreads(); // the single per-step block barrier

    // ---- combine + gates + publish: each wave finishes its own 4 rows ----
    if (lane < 4) {
      const int b = t & 1;
      const int row = 4 * wid + lane;
      float4 p0 = *(const float4*)&part[b][0][row][0];
      float4 p1 = *(const float4*)&part[b][1][row][0];
      float4 p2 = *(const float4*)&part[b][2][row][0];
      float4 p3 = *(const float4*)&part[b][3][row][0];
      float Ar = (p0.x + p1.x) + (p2.x + p3.x);
      float Az = (p0.y + p1.y) + (p2.y + p3.y);
      float Hn = (p0.z + p1.z) + (p2.z + p3.z);
      float rg = sigmoidf_fast(Ar + gxr0);
      float zg = sigmoidf_fast(Az + gxz0);
      float ng = tanhf_fast(gxn0 + rg * (Hn + bhn));
      float h  = (1.f - zg) * ng + zg * hold;
      hold = h;
      ull pk = ((ull)(uint)(t + 1) << 32) | (ull)__float_as_uint(h);
      __hip_atomic_store(hpairs + (size_t)(t & 1) * HID + e_cb, pk,
                         __ATOMIC_RELAXED, __HIP_MEMORY_SCOPE_AGENT);
      if (t >= SEG) grued[(size_t)(t - SEG) * HID + e_cb] = h;
      gxr0 = gxr1; gxz0 = gxz1; gxn0 = gxn1; xt1 = xt2;
    }
  }
}

// ---------------- stage 2: tiny GRU (H=1) over last 1024 states + fc2 ----------------
__global__ __launch_bounds__(TPB, 1) void gru_tail(
    const float* __restrict__ w_ih2,
    const float* __restrict__ w_hh2,
    const float* __restrict__ b_ih2,
    const float* __restrict__ b_hh2,
    const float* __restrict__ fc2_w,
    const float* __restrict__ fc2_b,
    float* __restrict__ out,
    const char* __restrict__ ws)
{
  const float* grued = (const float*)(ws + WS_GRUED);
  __shared__ float gx2s[LAST * 3];

  const int tid = threadIdx.x;
  const int g = tid >> 4, s = tid & 15;
  const float bi0 = b_ih2[0], bi1 = b_ih2[1], bi2 = b_ih2[2];

  const float4* w0 = (const float4*)(w_ih2 + 0 * HID + s * 64);
  const float4* w1 = (const float4*)(w_ih2 + 1 * HID + s * 64);
  const float4* w2 = (const float4*)(w_ih2 + 2 * HID + s * 64);

  for (int b = 0; b < LAST / 16; ++b) {
    const int row = b * 16 + g;
    const float4* gr4 = (const float4*)(grued + (size_t)row * HID + s * 64);
    float a0 = 0.f, a1 = 0.f, a2 = 0.f;
#pragma unroll
    for (int k = 0; k < 16; ++k) {
      float4 v = gr4[k], x0 = w0[k], x1 = w1[k], x2 = w2[k];
      a0 = fmaf(v.x, x0.x, a0); a0 = fmaf(v.y, x0.y, a0);
      a0 = fmaf(v.z, x0.z, a0); a0 = fmaf(v.w, x0.w, a0);
      a1 = fmaf(v.x, x1.x, a1); a1 = fmaf(v.y, x1.y, a1);
      a1 = fmaf(v.z, x1.z, a1); a1 = fmaf(v.w, x1.w, a1);
      a2 = fmaf(v.x, x2.x, a2); a2 = fmaf(v.y, x2.y, a2);
      a2 = fmaf(v.z, x2.z, a2); a2 = fmaf(v.w, x2.w, a2);
    }
#pragma unroll
    for (int m = 1; m < 16; m <<= 1) {
      a0 += __shfl_xor(a0, m, 64);
      a1 += __shfl_xor(a1, m, 64);
      a2 += __shfl_xor(a2, m, 64);
    }
    if (s == 0) {
      gx2s[row * 3 + 0] = a0 + bi0;
      gx2s[row * 3 + 1] = a1 + bi1;
      gx2s[row * 3 + 2] = a2 + bi2;
    }
  }
  __syncthreads();

  if (tid == 0) {
    float h2 = 0.f;
    float r0 = fc2_b[0], r1 = fc2_b[1];
    const float whr = w_hh2[0], whz = w_hh2[1], whn = w_hh2[2];
    const float bhr = b_hh2[0], bhz = b_hh2[1], bhn = b_hh2[2];
    for (int t = 0; t < LAST; ++t) {
      float gr_ = gx2s[t * 3 + 0];
      float gz_ = gx2s[t * 3 + 1];
      float gn_ = gx2s[t * 3 + 2];
      float r = sigmoidf_fast(gr_ + h2 * whr + bhr);
      float z = sigmoidf_fast(gz_ + h2 * whz + bhz);
      float n = tanhf_fast(gn_ + r * (h2 * whn + bhn));
      h2 = (1.f - z) * n + z * h2;
      r0 = fmaf(h2, fc2_w[t], r0);
      r1 = fmaf(h2, fc2_w[HID + t], r1);
    }
    out[0] = r0;
    out[1] = r1;
  }
}

extern "C" void kernel_launch(void* const* d_in, const int* in_sizes, int n_in,
                              void* d_out, int out_size, void* d_ws, size_t ws_size,
                              hipStream_t stream) {
  const int*   x     = (const int*)d_in[0];
  const float* emb   = (const float*)d_in[1];
  const float* w_ih  = (const float*)d_in[2];
  const float* w_hh  = (const float*)d_in[3];
  const float* b_ih  = (const float*)d_in[4];
  const float* b_hh  = (const float*)d_in[5];
  const float* w_ih2 = (const float*)d_in[6];
  const float* w_hh2 = (const float*)d_in[7];
  const float* b_ih2 = (const float*)d_in[8];
  const float* b_hh2 = (const float*)d_in[9];
  const float* fc2_w = (const float*)d_in[10];
  const float* fc2_b = (const float*)d_in[11];

  // tags must start at 0 EVERY call (stale tags from a prior replay could false-match)
  hipMemsetAsync(d_ws, 0, 20480, stream);

  gx_table<<<dim3(VOCAB), dim3(256), 0, stream>>>(
      emb, w_ih, b_ih, b_hh, (float*)((char*)d_ws + WS_GXTAB));
  gru_seq<<<dim3(NWG), dim3(TPB), 0, stream>>>(
      x, w_hh, b_hh, (char*)d_ws);
  gru_tail<<<dim3(1), dim3(TPB), 0, stream>>>(
      w_ih2, w_hh2, b_ih2, b_hh2, fc2_w, fc2_b, (float*)d_out, (const char*)d_ws);
}